// Round 16
// baseline (10302.566 us; speedup 1.0000x reference)
//
#include <hip/hip_runtime.h>
#include <hip/hip_bf16.h>

#define BATCH 8
#define SEQ   2048
#define DIM   1024
#define NLAYER 2

typedef float  f32x4 __attribute__((ext_vector_type(4)));
typedef short  s16x8 __attribute__((ext_vector_type(8)));
typedef unsigned short u16x4 __attribute__((ext_vector_type(4)));

// =====================================================================
// cheap bf16 split (r12): hi = HW RNE cast, lo = truncated residual
// =====================================================================
__device__ __forceinline__ void split_bf16(float x, unsigned short& hi, unsigned short& lo) {
  const __hip_bfloat16 hb = __float2bfloat16(x);          // HW RNE
  hi = *reinterpret_cast<const unsigned short*>(&hb);
  const float hf = __bfloat162float(hb);
  lo = (unsigned short)(__float_as_uint(x - hf) >> 16);   // truncate residual
}

// =====================================================================
// one-shot weight splitter: W (f32) -> Wh, Wl planes
// =====================================================================
__global__ __launch_bounds__(256)
void split_mat(const float* __restrict__ W, unsigned short* __restrict__ Wh,
               unsigned short* __restrict__ Wl)
{
  const int i = (blockIdx.x * 256 + threadIdx.x) * 4;
  const float4 v = *(const float4*)&W[i];
  unsigned short h0,h1,h2,h3,l0,l1,l2,l3;
  split_bf16(v.x, h0, l0); split_bf16(v.y, h1, l1);
  split_bf16(v.z, h2, l2); split_bf16(v.w, h3, l3);
  *(u16x4*)&Wh[i] = (u16x4){h0, h1, h2, h3};
  *(u16x4*)&Wl[i] = (u16x4){l0, l1, l2, l3};
}

// =====================================================================
// V transpose + split: V [SEQ][DIM] f32 -> Th,Tl [DIM][SEQ] u16 planes
// =====================================================================
__global__ __launch_bounds__(256)
void vtrans(const float* __restrict__ V, unsigned short* __restrict__ Th,
            unsigned short* __restrict__ Tl)
{
  __shared__ float t[64][65];
  const int z = blockIdx.z;
  V  += (size_t)z * SEQ * DIM;
  Th += (size_t)z * (size_t)DIM * SEQ;
  Tl += (size_t)z * (size_t)DIM * SEQ;
  const int s0 = blockIdx.x * 64, d0 = blockIdx.y * 64;
  const int tid = threadIdx.x;
#pragma unroll
  for (int rep = 0; rep < 4; ++rep) {
    const int idx = rep * 256 + tid;
    const int r = idx >> 4, c = idx & 15;
    const float4 v = *(const float4*)&V[(size_t)(s0 + r) * DIM + d0 + c * 4];
    t[c*4+0][r] = v.x; t[c*4+1][r] = v.y; t[c*4+2][r] = v.z; t[c*4+3][r] = v.w;
  }
  __syncthreads();
#pragma unroll
  for (int rep = 0; rep < 4; ++rep) {
    const int idx = rep * 256 + tid;
    const int r = idx >> 4, c = idx & 15;
    unsigned short h[4], l[4];
#pragma unroll
    for (int j = 0; j < 4; ++j) split_bf16(t[r][c*4+j], h[j], l[j]);
    const size_t off = (size_t)(d0 + r) * SEQ + s0 + c * 4;
    *(u16x4*)&Th[off] = (u16x4){h[0], h[1], h[2], h[3]};
    *(u16x4*)&Tl[off] = (u16x4){l[0], l[1], l[2], l[3]};
  }
}

// =====================================================================
// bf16x3 MFMA GEMM, A fp32 on-the-fly split, B pre-split planes (N x K).
// WS=1: epilogue writes split u16 planes. z-batched.
// =====================================================================
template<int WS>
__global__ __launch_bounds__(256)
void gemm_bsplit(const float* __restrict__ A,
                 const unsigned short* __restrict__ Bhg,
                 const unsigned short* __restrict__ Blg,
                 const float* __restrict__ bias, float* __restrict__ C,
                 unsigned short* __restrict__ Ch, unsigned short* __restrict__ Cl,
                 int M, int N, int K, float alpha,
                 long long sA, long long sB, long long sC)
{
  constexpr int LK = 40;
  __shared__ unsigned short Ah[128 * LK], Al[128 * LK];
  __shared__ unsigned short Bh[128 * LK], Bl[128 * LK];

  const int z = blockIdx.z;
  A += (size_t)z * sA;
  Bhg += (size_t)z * sB;  Blg += (size_t)z * sB;
  if (WS) { Ch += (size_t)z * sC; Cl += (size_t)z * sC; }
  else    { C  += (size_t)z * sC; }

  const int tid  = threadIdx.x;
  const int row0 = blockIdx.x * 128;
  const int col0 = blockIdx.y * 128;
  const int w    = tid >> 6;
  const int lane = tid & 63;
  const int m0   = (w >> 1) * 64;
  const int n0   = (w & 1) * 64;
  const int half = lane >> 4;
  const int mr   = lane & 15;

  f32x4 acc[4][4];
#pragma unroll
  for (int i = 0; i < 4; ++i)
#pragma unroll
    for (int j = 0; j < 4; ++j) acc[i][j] = (f32x4){0.f, 0.f, 0.f, 0.f};

  for (int k0 = 0; k0 < K; k0 += 32) {
    __syncthreads();
    {
      const int r = tid >> 3, c4 = tid & 7;
#pragma unroll
      for (int rep = 0; rep < 4; ++rep) {
        const int row = r + rep * 32;
        const float4 v = *(const float4*)&A[(size_t)(row0 + row) * K + k0 + c4 * 4];
        unsigned short h0,h1,h2,h3,l0,l1,l2,l3;
        split_bf16(v.x, h0, l0); split_bf16(v.y, h1, l1);
        split_bf16(v.z, h2, l2); split_bf16(v.w, h3, l3);
        *(u16x4*)&Ah[row * LK + c4 * 4] = (u16x4){h0, h1, h2, h3};
        *(u16x4*)&Al[row * LK + c4 * 4] = (u16x4){l0, l1, l2, l3};
      }
    }
    {
      const int r = tid >> 3, c4 = tid & 7;
#pragma unroll
      for (int rep = 0; rep < 4; ++rep) {
        const int row = r + rep * 32;
        const size_t off = (size_t)(col0 + row) * K + k0 + c4 * 4;
        *(u16x4*)&Bh[row * LK + c4 * 4] = *(const u16x4*)&Bhg[off];
        *(u16x4*)&Bl[row * LK + c4 * 4] = *(const u16x4*)&Blg[off];
      }
    }
    __syncthreads();

    s16x8 ah[4], al[4], bh[4], bl[4];
#pragma unroll
    for (int i = 0; i < 4; ++i) {
      ah[i] = *(const s16x8*)&Ah[(m0 + i*16 + mr) * LK + half * 8];
      al[i] = *(const s16x8*)&Al[(m0 + i*16 + mr) * LK + half * 8];
      bh[i] = *(const s16x8*)&Bh[(n0 + i*16 + mr) * LK + half * 8];
      bl[i] = *(const s16x8*)&Bl[(n0 + i*16 + mr) * LK + half * 8];
    }
#pragma unroll
    for (int i = 0; i < 4; ++i)
#pragma unroll
      for (int j = 0; j < 4; ++j) {
        acc[i][j] = __builtin_amdgcn_mfma_f32_16x16x32_bf16(ah[i], bh[j], acc[i][j], 0, 0, 0);
        acc[i][j] = __builtin_amdgcn_mfma_f32_16x16x32_bf16(ah[i], bl[j], acc[i][j], 0, 0, 0);
        acc[i][j] = __builtin_amdgcn_mfma_f32_16x16x32_bf16(al[i], bh[j], acc[i][j], 0, 0, 0);
      }
  }

#pragma unroll
  for (int j = 0; j < 4; ++j) {
    const int col = col0 + n0 + j * 16 + mr;
    const float bb = bias ? bias[col] : 0.f;
#pragma unroll
    for (int i = 0; i < 4; ++i) {
#pragma unroll
      for (int q = 0; q < 4; ++q) {
        const int row = row0 + m0 + i * 16 + half * 4 + q;
        const float val = fmaf(alpha, acc[i][j][q], bb);
        if (WS) {
          unsigned short h, l;
          split_bf16(val, h, l);
          Ch[(size_t)row * N + col] = h;
          Cl[(size_t)row * N + col] = l;
        } else {
          C[(size_t)row * N + col] = val;
        }
      }
    }
  }
}

// =====================================================================
// bf16x3 MFMA GEMM, BOTH operands pre-split. Zero split VALU. (QK^T)
// =====================================================================
__global__ __launch_bounds__(256)
void gemm_absplit(const unsigned short* __restrict__ Ahg,
                  const unsigned short* __restrict__ Alg,
                  const unsigned short* __restrict__ Bhg,
                  const unsigned short* __restrict__ Blg,
                  float* __restrict__ C,
                  int M, int N, int K, float alpha,
                  long long sA, long long sB, long long sC)
{
  constexpr int LK = 40;
  __shared__ unsigned short Ah[128 * LK], Al[128 * LK];
  __shared__ unsigned short Bh[128 * LK], Bl[128 * LK];

  const int z = blockIdx.z;
  Ahg += (size_t)z * sA;  Alg += (size_t)z * sA;
  Bhg += (size_t)z * sB;  Blg += (size_t)z * sB;
  C   += (size_t)z * sC;

  const int tid  = threadIdx.x;
  const int row0 = blockIdx.x * 128;
  const int col0 = blockIdx.y * 128;
  const int w    = tid >> 6;
  const int lane = tid & 63;
  const int m0   = (w >> 1) * 64;
  const int n0   = (w & 1) * 64;
  const int half = lane >> 4;
  const int mr   = lane & 15;

  f32x4 acc[4][4];
#pragma unroll
  for (int i = 0; i < 4; ++i)
#pragma unroll
    for (int j = 0; j < 4; ++j) acc[i][j] = (f32x4){0.f, 0.f, 0.f, 0.f};

  for (int k0 = 0; k0 < K; k0 += 32) {
    __syncthreads();
    {
      const int r = tid >> 3, c4 = tid & 7;
#pragma unroll
      for (int rep = 0; rep < 4; ++rep) {
        const int row = r + rep * 32;
        const size_t offA = (size_t)(row0 + row) * K + k0 + c4 * 4;
        *(u16x4*)&Ah[row * LK + c4 * 4] = *(const u16x4*)&Ahg[offA];
        *(u16x4*)&Al[row * LK + c4 * 4] = *(const u16x4*)&Alg[offA];
        const size_t offB = (size_t)(col0 + row) * K + k0 + c4 * 4;
        *(u16x4*)&Bh[row * LK + c4 * 4] = *(const u16x4*)&Bhg[offB];
        *(u16x4*)&Bl[row * LK + c4 * 4] = *(const u16x4*)&Blg[offB];
      }
    }
    __syncthreads();

    s16x8 ah[4], al[4], bh[4], bl[4];
#pragma unroll
    for (int i = 0; i < 4; ++i) {
      ah[i] = *(const s16x8*)&Ah[(m0 + i*16 + mr) * LK + half * 8];
      al[i] = *(const s16x8*)&Al[(m0 + i*16 + mr) * LK + half * 8];
      bh[i] = *(const s16x8*)&Bh[(n0 + i*16 + mr) * LK + half * 8];
      bl[i] = *(const s16x8*)&Bl[(n0 + i*16 + mr) * LK + half * 8];
    }
#pragma unroll
    for (int i = 0; i < 4; ++i)
#pragma unroll
      for (int j = 0; j < 4; ++j) {
        acc[i][j] = __builtin_amdgcn_mfma_f32_16x16x32_bf16(ah[i], bh[j], acc[i][j], 0, 0, 0);
        acc[i][j] = __builtin_amdgcn_mfma_f32_16x16x32_bf16(ah[i], bl[j], acc[i][j], 0, 0, 0);
        acc[i][j] = __builtin_amdgcn_mfma_f32_16x16x32_bf16(al[i], bh[j], acc[i][j], 0, 0, 0);
      }
  }

#pragma unroll
  for (int j = 0; j < 4; ++j) {
    const int col = col0 + n0 + j * 16 + mr;
#pragma unroll
    for (int i = 0; i < 4; ++i) {
#pragma unroll
      for (int q = 0; q < 4; ++q) {
        const int row = row0 + m0 + i * 16 + half * 4 + q;
        C[(size_t)row * N + col] = alpha * acc[i][j][q];
      }
    }
  }
}

// =====================================================================
// r12 on-the-fly GEMM (fallback path when ws too small)
// =====================================================================
template<int TRANSB>
__global__ __launch_bounds__(256)
void gemm_bf16x3(const float* __restrict__ A, const float* __restrict__ B,
                 const float* __restrict__ bias, float* __restrict__ C,
                 int M, int N, int K, float alpha,
                 long long strideA, long long strideB, long long strideC)
{
  constexpr int LK = 40;
  __shared__ unsigned short Ah[128 * LK], Al[128 * LK];
  __shared__ unsigned short Bh[128 * LK], Bl[128 * LK];

  const int z = blockIdx.z;
  A += (size_t)z * strideA;
  B += (size_t)z * strideB;
  C += (size_t)z * strideC;

  const int tid  = threadIdx.x;
  const int row0 = blockIdx.x * 128;
  const int col0 = blockIdx.y * 128;
  const int w    = tid >> 6;
  const int lane = tid & 63;
  const int m0   = (w >> 1) * 64;
  const int n0   = (w & 1) * 64;
  const int half = lane >> 4;
  const int mr   = lane & 15;

  f32x4 acc[4][4];
#pragma unroll
  for (int i = 0; i < 4; ++i)
#pragma unroll
    for (int j = 0; j < 4; ++j) acc[i][j] = (f32x4){0.f, 0.f, 0.f, 0.f};

  for (int k0 = 0; k0 < K; k0 += 32) {
    __syncthreads();
    {
      const int r = tid >> 3, c4 = tid & 7;
#pragma unroll
      for (int rep = 0; rep < 4; ++rep) {
        const int row = r + rep * 32;
        const float4 v = *(const float4*)&A[(size_t)(row0 + row) * K + k0 + c4 * 4];
        unsigned short h0,h1,h2,h3,l0,l1,l2,l3;
        split_bf16(v.x, h0, l0); split_bf16(v.y, h1, l1);
        split_bf16(v.z, h2, l2); split_bf16(v.w, h3, l3);
        *(u16x4*)&Ah[row * LK + c4 * 4] = (u16x4){h0, h1, h2, h3};
        *(u16x4*)&Al[row * LK + c4 * 4] = (u16x4){l0, l1, l2, l3};
      }
    }
    if (TRANSB) {
      const int r = tid >> 3, c4 = tid & 7;
#pragma unroll
      for (int rep = 0; rep < 4; ++rep) {
        const int row = r + rep * 32;
        const float4 v = *(const float4*)&B[(size_t)(col0 + row) * K + k0 + c4 * 4];
        unsigned short h0,h1,h2,h3,l0,l1,l2,l3;
        split_bf16(v.x, h0, l0); split_bf16(v.y, h1, l1);
        split_bf16(v.z, h2, l2); split_bf16(v.w, h3, l3);
        *(u16x4*)&Bh[row * LK + c4 * 4] = (u16x4){h0, h1, h2, h3};
        *(u16x4*)&Bl[row * LK + c4 * 4] = (u16x4){l0, l1, l2, l3};
      }
    } else {
      const int kk8 = tid >> 5, n4 = tid & 31;
#pragma unroll
      for (int rep = 0; rep < 4; ++rep) {
        const int kk = kk8 + rep * 8;
        const float4 v = *(const float4*)&B[(size_t)(k0 + kk) * N + col0 + n4 * 4];
        unsigned short h, l;
        split_bf16(v.x, h, l); Bh[(n4*4+0)*LK + kk] = h; Bl[(n4*4+0)*LK + kk] = l;
        split_bf16(v.y, h, l); Bh[(n4*4+1)*LK + kk] = h; Bl[(n4*4+1)*LK + kk] = l;
        split_bf16(v.z, h, l); Bh[(n4*4+2)*LK + kk] = h; Bl[(n4*4+2)*LK + kk] = l;
        split_bf16(v.w, h, l); Bh[(n4*4+3)*LK + kk] = h; Bl[(n4*4+3)*LK + kk] = l;
      }
    }
    __syncthreads();

    s16x8 ah[4], al[4], bh[4], bl[4];
#pragma unroll
    for (int i = 0; i < 4; ++i) {
      ah[i] = *(const s16x8*)&Ah[(m0 + i*16 + mr) * LK + half * 8];
      al[i] = *(const s16x8*)&Al[(m0 + i*16 + mr) * LK + half * 8];
      bh[i] = *(const s16x8*)&Bh[(n0 + i*16 + mr) * LK + half * 8];
      bl[i] = *(const s16x8*)&Bl[(n0 + i*16 + mr) * LK + half * 8];
    }
#pragma unroll
    for (int i = 0; i < 4; ++i)
#pragma unroll
      for (int j = 0; j < 4; ++j) {
        acc[i][j] = __builtin_amdgcn_mfma_f32_16x16x32_bf16(ah[i], bh[j], acc[i][j], 0, 0, 0);
        acc[i][j] = __builtin_amdgcn_mfma_f32_16x16x32_bf16(ah[i], bl[j], acc[i][j], 0, 0, 0);
        acc[i][j] = __builtin_amdgcn_mfma_f32_16x16x32_bf16(al[i], bh[j], acc[i][j], 0, 0, 0);
      }
  }

#pragma unroll
  for (int j = 0; j < 4; ++j) {
    const int col = col0 + n0 + j * 16 + mr;
    const float bb = bias ? bias[col] : 0.f;
#pragma unroll
    for (int i = 0; i < 4; ++i) {
#pragma unroll
      for (int q = 0; q < 4; ++q) {
        const int row = row0 + m0 + i * 16 + half * 4 + q;
        C[(size_t)row * N + col] = fmaf(alpha, acc[i][j][q], bb);
      }
    }
  }
}

// =====================================================================
// tanh without an OCML call (abs err ~1e-7)
// =====================================================================
__device__ __forceinline__ float fast_tanh(float x) {
  const float a = fabsf(x);
  const float e = __expf(2.0f * a);
  const float t = 1.0f - 2.0f / (e + 1.0f);
  return copysignf(t, x);
}

// =====================================================================
// RNN scan v11 = r11's v9 with the communication path tightened:
//  1. SLOW-PROBE-ONLY poll: r8-r15's fast(sc0)+slow(sc0sc1) serial
//     iteration was ~800ns; timing decomposition says the fast probe
//     almost never hits (r8: dual gained only 11% over slow-only), so
//     it just doubled the sampling period. Now each iteration is one
//     sc0sc1 probe (~450ns) -> detection latency drops ~2x sampling
//     penalty. Progress guaranteed (probe reaches L3; producer writes
//     through).
//  2. GROUPED dwordx4 dual-store: wave0 routes tanh results through a
//     32-float LDS row (same-wave, no barrier), lanes 0-7 issue two
//     dwordx4 stores -> 8 transactions/line instead of 32 -> faster
//     full-line visibility, less skew. Detection still checks EVERY
//     dword, so no atomicity assumption.
// Values and arithmetic order unchanged -> scan BIT-IDENTICAL
// (canary: absmax exactly 0.0009765625).
// =====================================================================
__global__ __launch_bounds__(512, 1)
void rnn_scan(const float* __restrict__ Pre, float* __restrict__ Hout,
              const float* __restrict__ Whh, const float* __restrict__ bhh)
{
  __shared__ float wS[32][DIM];                 // 128 KB
  __shared__ __align__(16) float hbuf[2][DIM];  // 8 KB
  __shared__ float pS[8][8];
  __shared__ __align__(16) float hout[32];
  const int b    = blockIdx.x & 7;
  const int p    = blockIdx.x >> 3;      // 0..31
  const int wv   = threadIdx.x >> 6;     // 0..7
  const int lane = threadIdx.x & 63;
  const int fl   = ((lane & 1) << 1) | ((lane >> 1) & 1);  // bitrev2

  const float* PreB = Pre  + (size_t)b * SEQ * DIM;
  float*       HB   = Hout + (size_t)b * SEQ * DIM;

  for (int i = threadIdx.x; i < 32 * (DIM / 4); i += 512) {
    const int row = i >> 8, c4 = i & 255;
    *(f32x4*)&wS[row][c4 * 4] =
        *(const f32x4*)&Whh[(size_t)(p * 32 + row) * DIM + c4 * 4];
  }
  __syncthreads();

  const bool w0lane = (wv == 0) && (lane < 32);
  const float biasv = w0lane ? bhh[p * 32 + lane] : 0.f;

  for (int t = 0; t < SEQ; ++t) {
    // ---- h-independent hoists: overlap wave0's poll ----
    float pre = 0.f;
    if (w0lane) pre = PreB[(size_t)t * DIM + p * 32 + lane];

    f32x4 wr[4][4];
    if (wv != 0) {
#pragma unroll
      for (int r = 0; r < 4; ++r) {
        wr[r][0] = *(const f32x4*)&wS[wv * 4 + r][  0 + lane * 4];
        wr[r][1] = *(const f32x4*)&wS[wv * 4 + r][256 + lane * 4];
        wr[r][2] = *(const f32x4*)&wS[wv * 4 + r][512 + lane * 4];
        wr[r][3] = *(const f32x4*)&wS[wv * 4 + r][768 + lane * 4];
      }
    }

    if (t > 0) {
      if (wv == 0) {
        const float* hp = HB + (size_t)(t - 1) * DIM;
        const float* q0 = hp +   0 + lane * 4;
        const float* q1 = hp + 256 + lane * 4;
        const float* q2 = hp + 512 + lane * 4;
        const float* q3 = hp + 768 + lane * 4;
        f32x4 m0, m1, m2, m3;
        while (true) {            // single slow probe per iteration
          asm volatile(
            "global_load_dwordx4 %0, %4, off sc0 sc1\n\t"
            "global_load_dwordx4 %1, %5, off sc0 sc1\n\t"
            "global_load_dwordx4 %2, %6, off sc0 sc1\n\t"
            "global_load_dwordx4 %3, %7, off sc0 sc1\n\t"
            "s_waitcnt vmcnt(0)"
            : "=&v"(m0), "=&v"(m1), "=&v"(m2), "=&v"(m3)
            : "v"(q0), "v"(q1), "v"(q2), "v"(q3));
          bool g = true;
#pragma unroll
          for (int j = 0; j < 4; ++j) {
            g = g && (__float_as_uint(m0[j]) != 0xFFFFFFFFu)
                  && (__float_as_uint(m1[j]) != 0xFFFFFFFFu)
                  && (__float_as_uint(m2[j]) != 0xFFFFFFFFu)
                  && (__float_as_uint(m3[j]) != 0xFFFFFFFFu);
          }
          if (__all(g)) break;
        }
        *(f32x4*)&hbuf[t & 1][  0 + lane * 4] = m0;
        *(f32x4*)&hbuf[t & 1][256 + lane * 4] = m1;
        *(f32x4*)&hbuf[t & 1][512 + lane * 4] = m2;
        *(f32x4*)&hbuf[t & 1][768 + lane * 4] = m3;
        // wave0 prefetch: issues now, completes under the barrier wait
#pragma unroll
        for (int r = 0; r < 4; ++r) {
          wr[r][0] = *(const f32x4*)&wS[wv * 4 + r][  0 + lane * 4];
          wr[r][1] = *(const f32x4*)&wS[wv * 4 + r][256 + lane * 4];
          wr[r][2] = *(const f32x4*)&wS[wv * 4 + r][512 + lane * 4];
          wr[r][3] = *(const f32x4*)&wS[wv * 4 + r][768 + lane * 4];
        }
      }
      __syncthreads();   // A: hbuf ready
      const f32x4 h0 = *(const f32x4*)&hbuf[t & 1][  0 + lane * 4];
      const f32x4 h1 = *(const f32x4*)&hbuf[t & 1][256 + lane * 4];
      const f32x4 h2 = *(const f32x4*)&hbuf[t & 1][512 + lane * 4];
      const f32x4 h3 = *(const f32x4*)&hbuf[t & 1][768 + lane * 4];
      float acc[4];
#pragma unroll
      for (int r = 0; r < 4; ++r) {
        float a = 0.f;
        a = fmaf(wr[r][0].x, h0.x, fmaf(wr[r][0].y, h0.y,
            fmaf(wr[r][0].z, h0.z, fmaf(wr[r][0].w, h0.w, a))));
        a = fmaf(wr[r][1].x, h1.x, fmaf(wr[r][1].y, h1.y,
            fmaf(wr[r][1].z, h1.z, fmaf(wr[r][1].w, h1.w, a))));
        a = fmaf(wr[r][2].x, h2.x, fmaf(wr[r][2].y, h2.y,
            fmaf(wr[r][2].z, h2.z, fmaf(wr[r][2].w, h2.w, a))));
        a = fmaf(wr[r][3].x, h3.x, fmaf(wr[r][3].y, h3.y,
            fmaf(wr[r][3].z, h3.z, fmaf(wr[r][3].w, h3.w, a))));
        acc[r] = a;
      }
#pragma unroll
      for (int m = 0; m < 2; ++m) {
        const int mask = 1 << m;
        const int nv   = 2 >> m;
        const bool up  = (lane & mask) != 0;
#pragma unroll
        for (int r = 0; r < nv; ++r) {
          const float lo = up ? acc[r + nv] : acc[r];
          const float hi = up ? acc[r] : acc[r + nv];
          acc[r] = lo + __shfl_xor(hi, mask);
        }
      }
#pragma unroll
      for (int off = 4; off < 64; off <<= 1) acc[0] += __shfl_xor(acc[0], off);

      if (lane < 4) pS[wv][fl] = acc[0];
      __syncthreads();   // B: pS ready
    }

    if (wv == 0) {
      if (lane < 32) {
        float s = (t > 0) ? (pre + pS[lane >> 2][lane & 3] + biasv)
                          : (pre + biasv);
        hout[lane] = fast_tanh(s);
      }
      // same-wave LDS write->read (lockstep, compiler inserts lgkmcnt)
      if (lane < 8) {
        const f32x4 hv = *(const f32x4*)&hout[lane * 4];
        float* dst = HB + (size_t)t * DIM + p * 32 + lane * 4;
        asm volatile(
          "global_store_dwordx4 %0, %1, off sc0\n\t"      // fast: own-XCD L2
          "global_store_dwordx4 %0, %1, off sc0 sc1"      // slow: through to L3
          :: "v"(dst), "v"(hv));
      }
    }
  }
}

// =====================================================================
// Masked softmax, in place, one row per block
// =====================================================================
__global__ __launch_bounds__(256)
void softmax_mask(float* __restrict__ S, const unsigned char* __restrict__ mask)
{
  const size_t row = (size_t)blockIdx.y * gridDim.x + blockIdx.x;
  float* p = S + row * SEQ;
  const unsigned char* mrow = mask + row * SEQ;
  __shared__ float buf[SEQ];
  __shared__ float red[4];
  const int tid = threadIdx.x, lane = tid & 63, wv = tid >> 6;

  float mx = -1e30f;
  for (int i = tid; i < SEQ; i += 256) {
    const float v = mrow[i] ? -1e9f : p[i];
    buf[i] = v;
    mx = fmaxf(mx, v);
  }
#pragma unroll
  for (int off = 1; off < 64; off <<= 1) mx = fmaxf(mx, __shfl_xor(mx, off));
  if (lane == 0) red[wv] = mx;
  __syncthreads();
  mx = fmaxf(fmaxf(red[0], red[1]), fmaxf(red[2], red[3]));

  float s = 0.f;
  for (int i = tid; i < SEQ; i += 256) {
    const float e = __expf(buf[i] - mx);
    buf[i] = e;
    s += e;
  }
#pragma unroll
  for (int off = 1; off < 64; off <<= 1) s += __shfl_xor(s, off);
  __syncthreads();
  if (lane == 0) red[wv] = s;
  __syncthreads();
  s = red[0] + red[1] + red[2] + red[3];
  const float inv = 1.f / s;
  for (int i = tid; i < SEQ; i += 256) p[i] = buf[i] * inv;
}

// =====================================================================
extern "C" void kernel_launch(void* const* d_in, const int* in_sizes, int n_in,
                              void* d_out, int out_size, void* d_ws, size_t ws_size,
                              hipStream_t stream)
{
  (void)in_sizes; (void)n_in; (void)out_size;
  const unsigned char* mask = (const unsigned char*)d_in[0];
  const float* reps = (const float*)d_in[1];
  const float* Wih  = (const float*)d_in[2];
  const float* Whh  = (const float*)d_in[3];
  const float* bih  = (const float*)d_in[4];
  const float* bhh  = (const float*)d_in[5];
  const float* Wq   = (const float*)d_in[6];
  const float* bq   = (const float*)d_in[7];
  const float* Wk   = (const float*)d_in[8];
  const float* bk   = (const float*)d_in[9];
  const float* Wv   = (const float*)d_in[10];
  const float* bv   = (const float*)d_in[11];
  const float* Wo   = (const float*)d_in[12];
  const float* bo   = (const float*)d_in[13];
  float* out = (float*)d_out;

  char* ws = (char*)d_ws;
  float* Hb = (float*)(ws);
  float* Qb = (float*)(ws + ((size_t)64  << 20));
  float* Kb = (float*)(ws + ((size_t)128 << 20));
  float* Vb = (float*)(ws + ((size_t)192 << 20));
  float* Sb = (float*)(ws + ((size_t)256 << 20));
  const size_t needFull = ((size_t)256 << 20) + (size_t)BATCH * SEQ * SEQ * 4;
  const bool fullS = ws_size >= needFull;
  const size_t MM = (size_t)DIM * DIM;
  unsigned short* wsp = (unsigned short*)(ws + needFull);
  const bool presplit = fullS && (ws_size >= needFull + ((size_t)20 << 20));
  const size_t hBytes = (size_t)BATCH * SEQ * DIM * 4;

  const int M1 = BATCH * SEQ;
  const size_t PL = (size_t)M1 * DIM;
  const float scale = 0.03125f;
  const dim3 blk(256);
  const dim3 projGrid(M1/128, DIM/128, 1);
  const long long sSD = (long long)SEQ * DIM;
  const long long sSS = (long long)SEQ * SEQ;
  const int splitGrid = (int)(MM / (256 * 4));

  unsigned short* Qh = (unsigned short*)Qb;  unsigned short* Ql = Qh + PL;
  unsigned short* Kh = (unsigned short*)Kb;  unsigned short* Kl = Kh + PL;
  unsigned short* Vth = (unsigned short*)Vb; unsigned short* Vtl = Vth + PL;

  const float* X = reps;
  for (int l = 0; l < NLAYER; ++l) {
    const size_t wof = (size_t)l * DIM * DIM;
    const size_t bof = (size_t)l * DIM;
    float* Y = (l == NLAYER - 1) ? out : Qb;

    hipMemsetAsync(Hb, 0xFF, hBytes, stream);
    if (presplit) {
      split_mat<<<splitGrid, blk, 0, stream>>>(Wih + wof, wsp + 0*MM, wsp + 1*MM);
      split_mat<<<splitGrid, blk, 0, stream>>>(Wq  + wof, wsp + 2*MM, wsp + 3*MM);
      split_mat<<<splitGrid, blk, 0, stream>>>(Wk  + wof, wsp + 4*MM, wsp + 5*MM);
      split_mat<<<splitGrid, blk, 0, stream>>>(Wv  + wof, wsp + 6*MM, wsp + 7*MM);
      split_mat<<<splitGrid, blk, 0, stream>>>(Wo  + wof, wsp + 8*MM, wsp + 9*MM);

      gemm_bsplit<0><<<projGrid, blk, 0, stream>>>(
          X, wsp + 0*MM, wsp + 1*MM, bih + bof, Kb, nullptr, nullptr,
          M1, DIM, DIM, 1.f, 0, 0, 0);
      rnn_scan<<<dim3(256), dim3(512), 0, stream>>>(Kb, Hb, Whh + wof, bhh + bof);

      gemm_bsplit<1><<<projGrid, blk, 0, stream>>>(
          Hb, wsp + 2*MM, wsp + 3*MM, bq + bof, nullptr, Qh, Ql,
          M1, DIM, DIM, 1.f, 0, 0, 0);
      gemm_bsplit<1><<<projGrid, blk, 0, stream>>>(
          Hb, wsp + 4*MM, wsp + 5*MM, bk + bof, nullptr, Kh, Kl,
          M1, DIM, DIM, 1.f, 0, 0, 0);
      gemm_bsplit<0><<<projGrid, blk, 0, stream>>>(
          Hb, wsp + 6*MM, wsp + 7*MM, bv + bof, Sb, nullptr, nullptr,
          M1, DIM, DIM, 1.f, 0, 0, 0);
      vtrans<<<dim3(SEQ/64, DIM/64, BATCH), blk, 0, stream>>>(Sb, Vth, Vtl);

      gemm_absplit<<<dim3(SEQ/128, SEQ/128, BATCH), blk, 0, stream>>>(
          Qh, Ql, Kh, Kl, Sb, SEQ, SEQ, DIM, scale, sSD, sSD, sSS);
      softmax_mask<<<dim3(SEQ, BATCH), blk, 0, stream>>>(Sb, mask);
      gemm_bsplit<0><<<dim3(SEQ/128, DIM/128, BATCH), blk, 0, stream>>>(
          Sb, Vth, Vtl, nullptr, Hb, nullptr, nullptr,
          SEQ, DIM, SEQ, 1.f, sSS, (long long)DIM * SEQ, sSD);
      gemm_bsplit<0><<<projGrid, blk, 0, stream>>>(
          Hb, wsp + 8*MM, wsp + 9*MM, bo + bof, Y, nullptr, nullptr,
          M1, DIM, DIM, 1.f, 0, 0, 0);
    } else {
      gemm_bf16x3<1><<<projGrid, blk, 0, stream>>>(
          X, Wih + wof, bih + bof, Kb, M1, DIM, DIM, 1.f, 0, 0, 0);
      rnn_scan<<<dim3(256), dim3(512), 0, stream>>>(Kb, Hb, Whh + wof, bhh + bof);
      gemm_bf16x3<1><<<projGrid, blk, 0, stream>>>(
          Hb, Wq + wof, bq + bof, Qb, M1, DIM, DIM, 1.f, 0, 0, 0);
      gemm_bf16x3<1><<<projGrid, blk, 0, stream>>>(
          Hb, Wk + wof, bk + bof, Kb, M1, DIM, DIM, 1.f, 0, 0, 0);
      gemm_bf16x3<1><<<projGrid, blk, 0, stream>>>(
          Hb, Wv + wof, bv + bof, Vb, M1, DIM, DIM, 1.f, 0, 0, 0);
      if (fullS) {
        gemm_bf16x3<1><<<dim3(SEQ/128, SEQ/128, BATCH), blk, 0, stream>>>(
            Qb, Kb, nullptr, Sb, SEQ, SEQ, DIM, scale, sSD, sSD, sSS);
        softmax_mask<<<dim3(SEQ, BATCH), blk, 0, stream>>>(Sb, mask);
        gemm_bf16x3<0><<<dim3(SEQ/128, DIM/128, BATCH), blk, 0, stream>>>(
            Sb, Vb, nullptr, Hb, SEQ, DIM, SEQ, 1.f, sSS, sSD, sSD);
      } else {
        for (int bb = 0; bb < BATCH; ++bb) {
          gemm_bf16x3<1><<<dim3(SEQ/128, SEQ/128, 1), blk, 0, stream>>>(
              Qb + (size_t)bb * sSD, Kb + (size_t)bb * sSD, nullptr, Sb,
              SEQ, SEQ, DIM, scale, 0, 0, 0);
          softmax_mask<<<dim3(SEQ, 1), blk, 0, stream>>>(Sb, mask + (size_t)bb * sSS);
          gemm_bf16x3<0><<<dim3(SEQ/128, DIM/128, 1), blk, 0, stream>>>(
              Sb, Vb + (size_t)bb * sSD, nullptr, Hb + (size_t)bb * sSD,
              SEQ, DIM, SEQ, 1.f, 0, 0, 0);
        }
      }
      gemm_bf16x3<1><<<projGrid, blk, 0, stream>>>(
          Hb, Wo + wof, bo + bof, Y, M1, DIM, DIM, 1.f, 0, 0, 0);
    }
    X = Y;
  }
}

// Round 17
// 10152.502 us; speedup vs baseline: 1.0148x; 1.0148x over previous
//
#include <hip/hip_runtime.h>
#include <hip/hip_bf16.h>

#define BATCH 8
#define SEQ   2048
#define DIM   1024
#define NLAYER 2

typedef float  f32x4 __attribute__((ext_vector_type(4)));
typedef short  s16x8 __attribute__((ext_vector_type(8)));
typedef unsigned short u16x4 __attribute__((ext_vector_type(4)));

// =====================================================================
// cheap bf16 split (r12): hi = HW RNE cast, lo = truncated residual
// =====================================================================
__device__ __forceinline__ void split_bf16(float x, unsigned short& hi, unsigned short& lo) {
  const __hip_bfloat16 hb = __float2bfloat16(x);          // HW RNE
  hi = *reinterpret_cast<const unsigned short*>(&hb);
  const float hf = __bfloat162float(hb);
  lo = (unsigned short)(__float_as_uint(x - hf) >> 16);   // truncate residual
}

// =====================================================================
// one-shot weight splitter: W (f32) -> Wh, Wl planes
// =====================================================================
__global__ __launch_bounds__(256)
void split_mat(const float* __restrict__ W, unsigned short* __restrict__ Wh,
               unsigned short* __restrict__ Wl)
{
  const int i = (blockIdx.x * 256 + threadIdx.x) * 4;
  const float4 v = *(const float4*)&W[i];
  unsigned short h0,h1,h2,h3,l0,l1,l2,l3;
  split_bf16(v.x, h0, l0); split_bf16(v.y, h1, l1);
  split_bf16(v.z, h2, l2); split_bf16(v.w, h3, l3);
  *(u16x4*)&Wh[i] = (u16x4){h0, h1, h2, h3};
  *(u16x4*)&Wl[i] = (u16x4){l0, l1, l2, l3};
}

// =====================================================================
// V transpose + split: V [SEQ][DIM] f32 -> Th,Tl [DIM][SEQ] u16 planes
// =====================================================================
__global__ __launch_bounds__(256)
void vtrans(const float* __restrict__ V, unsigned short* __restrict__ Th,
            unsigned short* __restrict__ Tl)
{
  __shared__ float t[64][65];
  const int z = blockIdx.z;
  V  += (size_t)z * SEQ * DIM;
  Th += (size_t)z * (size_t)DIM * SEQ;
  Tl += (size_t)z * (size_t)DIM * SEQ;
  const int s0 = blockIdx.x * 64, d0 = blockIdx.y * 64;
  const int tid = threadIdx.x;
#pragma unroll
  for (int rep = 0; rep < 4; ++rep) {
    const int idx = rep * 256 + tid;
    const int r = idx >> 4, c = idx & 15;
    const float4 v = *(const float4*)&V[(size_t)(s0 + r) * DIM + d0 + c * 4];
    t[c*4+0][r] = v.x; t[c*4+1][r] = v.y; t[c*4+2][r] = v.z; t[c*4+3][r] = v.w;
  }
  __syncthreads();
#pragma unroll
  for (int rep = 0; rep < 4; ++rep) {
    const int idx = rep * 256 + tid;
    const int r = idx >> 4, c = idx & 15;
    unsigned short h[4], l[4];
#pragma unroll
    for (int j = 0; j < 4; ++j) split_bf16(t[r][c*4+j], h[j], l[j]);
    const size_t off = (size_t)(d0 + r) * SEQ + s0 + c * 4;
    *(u16x4*)&Th[off] = (u16x4){h[0], h[1], h[2], h[3]};
    *(u16x4*)&Tl[off] = (u16x4){l[0], l[1], l[2], l[3]};
  }
}

// =====================================================================
// bf16x3 MFMA GEMM, A fp32 on-the-fly split, B pre-split planes (N x K).
// WS=1: epilogue writes split u16 planes. z-batched.
// =====================================================================
template<int WS>
__global__ __launch_bounds__(256)
void gemm_bsplit(const float* __restrict__ A,
                 const unsigned short* __restrict__ Bhg,
                 const unsigned short* __restrict__ Blg,
                 const float* __restrict__ bias, float* __restrict__ C,
                 unsigned short* __restrict__ Ch, unsigned short* __restrict__ Cl,
                 int M, int N, int K, float alpha,
                 long long sA, long long sB, long long sC)
{
  constexpr int LK = 40;
  __shared__ unsigned short Ah[128 * LK], Al[128 * LK];
  __shared__ unsigned short Bh[128 * LK], Bl[128 * LK];

  const int z = blockIdx.z;
  A += (size_t)z * sA;
  Bhg += (size_t)z * sB;  Blg += (size_t)z * sB;
  if (WS) { Ch += (size_t)z * sC; Cl += (size_t)z * sC; }
  else    { C  += (size_t)z * sC; }

  const int tid  = threadIdx.x;
  const int row0 = blockIdx.x * 128;
  const int col0 = blockIdx.y * 128;
  const int w    = tid >> 6;
  const int lane = tid & 63;
  const int m0   = (w >> 1) * 64;
  const int n0   = (w & 1) * 64;
  const int half = lane >> 4;
  const int mr   = lane & 15;

  f32x4 acc[4][4];
#pragma unroll
  for (int i = 0; i < 4; ++i)
#pragma unroll
    for (int j = 0; j < 4; ++j) acc[i][j] = (f32x4){0.f, 0.f, 0.f, 0.f};

  for (int k0 = 0; k0 < K; k0 += 32) {
    __syncthreads();
    {
      const int r = tid >> 3, c4 = tid & 7;
#pragma unroll
      for (int rep = 0; rep < 4; ++rep) {
        const int row = r + rep * 32;
        const float4 v = *(const float4*)&A[(size_t)(row0 + row) * K + k0 + c4 * 4];
        unsigned short h0,h1,h2,h3,l0,l1,l2,l3;
        split_bf16(v.x, h0, l0); split_bf16(v.y, h1, l1);
        split_bf16(v.z, h2, l2); split_bf16(v.w, h3, l3);
        *(u16x4*)&Ah[row * LK + c4 * 4] = (u16x4){h0, h1, h2, h3};
        *(u16x4*)&Al[row * LK + c4 * 4] = (u16x4){l0, l1, l2, l3};
      }
    }
    {
      const int r = tid >> 3, c4 = tid & 7;
#pragma unroll
      for (int rep = 0; rep < 4; ++rep) {
        const int row = r + rep * 32;
        const size_t off = (size_t)(col0 + row) * K + k0 + c4 * 4;
        *(u16x4*)&Bh[row * LK + c4 * 4] = *(const u16x4*)&Bhg[off];
        *(u16x4*)&Bl[row * LK + c4 * 4] = *(const u16x4*)&Blg[off];
      }
    }
    __syncthreads();

    s16x8 ah[4], al[4], bh[4], bl[4];
#pragma unroll
    for (int i = 0; i < 4; ++i) {
      ah[i] = *(const s16x8*)&Ah[(m0 + i*16 + mr) * LK + half * 8];
      al[i] = *(const s16x8*)&Al[(m0 + i*16 + mr) * LK + half * 8];
      bh[i] = *(const s16x8*)&Bh[(n0 + i*16 + mr) * LK + half * 8];
      bl[i] = *(const s16x8*)&Bl[(n0 + i*16 + mr) * LK + half * 8];
    }
#pragma unroll
    for (int i = 0; i < 4; ++i)
#pragma unroll
      for (int j = 0; j < 4; ++j) {
        acc[i][j] = __builtin_amdgcn_mfma_f32_16x16x32_bf16(ah[i], bh[j], acc[i][j], 0, 0, 0);
        acc[i][j] = __builtin_amdgcn_mfma_f32_16x16x32_bf16(ah[i], bl[j], acc[i][j], 0, 0, 0);
        acc[i][j] = __builtin_amdgcn_mfma_f32_16x16x32_bf16(al[i], bh[j], acc[i][j], 0, 0, 0);
      }
  }

#pragma unroll
  for (int j = 0; j < 4; ++j) {
    const int col = col0 + n0 + j * 16 + mr;
    const float bb = bias ? bias[col] : 0.f;
#pragma unroll
    for (int i = 0; i < 4; ++i) {
#pragma unroll
      for (int q = 0; q < 4; ++q) {
        const int row = row0 + m0 + i * 16 + half * 4 + q;
        const float val = fmaf(alpha, acc[i][j][q], bb);
        if (WS) {
          unsigned short h, l;
          split_bf16(val, h, l);
          Ch[(size_t)row * N + col] = h;
          Cl[(size_t)row * N + col] = l;
        } else {
          C[(size_t)row * N + col] = val;
        }
      }
    }
  }
}

// =====================================================================
// bf16x3 MFMA GEMM, BOTH operands pre-split. Zero split VALU. (QK^T)
// =====================================================================
__global__ __launch_bounds__(256)
void gemm_absplit(const unsigned short* __restrict__ Ahg,
                  const unsigned short* __restrict__ Alg,
                  const unsigned short* __restrict__ Bhg,
                  const unsigned short* __restrict__ Blg,
                  float* __restrict__ C,
                  int M, int N, int K, float alpha,
                  long long sA, long long sB, long long sC)
{
  constexpr int LK = 40;
  __shared__ unsigned short Ah[128 * LK], Al[128 * LK];
  __shared__ unsigned short Bh[128 * LK], Bl[128 * LK];

  const int z = blockIdx.z;
  Ahg += (size_t)z * sA;  Alg += (size_t)z * sA;
  Bhg += (size_t)z * sB;  Blg += (size_t)z * sB;
  C   += (size_t)z * sC;

  const int tid  = threadIdx.x;
  const int row0 = blockIdx.x * 128;
  const int col0 = blockIdx.y * 128;
  const int w    = tid >> 6;
  const int lane = tid & 63;
  const int m0   = (w >> 1) * 64;
  const int n0   = (w & 1) * 64;
  const int half = lane >> 4;
  const int mr   = lane & 15;

  f32x4 acc[4][4];
#pragma unroll
  for (int i = 0; i < 4; ++i)
#pragma unroll
    for (int j = 0; j < 4; ++j) acc[i][j] = (f32x4){0.f, 0.f, 0.f, 0.f};

  for (int k0 = 0; k0 < K; k0 += 32) {
    __syncthreads();
    {
      const int r = tid >> 3, c4 = tid & 7;
#pragma unroll
      for (int rep = 0; rep < 4; ++rep) {
        const int row = r + rep * 32;
        const size_t offA = (size_t)(row0 + row) * K + k0 + c4 * 4;
        *(u16x4*)&Ah[row * LK + c4 * 4] = *(const u16x4*)&Ahg[offA];
        *(u16x4*)&Al[row * LK + c4 * 4] = *(const u16x4*)&Alg[offA];
        const size_t offB = (size_t)(col0 + row) * K + k0 + c4 * 4;
        *(u16x4*)&Bh[row * LK + c4 * 4] = *(const u16x4*)&Bhg[offB];
        *(u16x4*)&Bl[row * LK + c4 * 4] = *(const u16x4*)&Blg[offB];
      }
    }
    __syncthreads();

    s16x8 ah[4], al[4], bh[4], bl[4];
#pragma unroll
    for (int i = 0; i < 4; ++i) {
      ah[i] = *(const s16x8*)&Ah[(m0 + i*16 + mr) * LK + half * 8];
      al[i] = *(const s16x8*)&Al[(m0 + i*16 + mr) * LK + half * 8];
      bh[i] = *(const s16x8*)&Bh[(n0 + i*16 + mr) * LK + half * 8];
      bl[i] = *(const s16x8*)&Bl[(n0 + i*16 + mr) * LK + half * 8];
    }
#pragma unroll
    for (int i = 0; i < 4; ++i)
#pragma unroll
      for (int j = 0; j < 4; ++j) {
        acc[i][j] = __builtin_amdgcn_mfma_f32_16x16x32_bf16(ah[i], bh[j], acc[i][j], 0, 0, 0);
        acc[i][j] = __builtin_amdgcn_mfma_f32_16x16x32_bf16(ah[i], bl[j], acc[i][j], 0, 0, 0);
        acc[i][j] = __builtin_amdgcn_mfma_f32_16x16x32_bf16(al[i], bh[j], acc[i][j], 0, 0, 0);
      }
  }

#pragma unroll
  for (int j = 0; j < 4; ++j) {
    const int col = col0 + n0 + j * 16 + mr;
#pragma unroll
    for (int i = 0; i < 4; ++i) {
#pragma unroll
      for (int q = 0; q < 4; ++q) {
        const int row = row0 + m0 + i * 16 + half * 4 + q;
        C[(size_t)row * N + col] = alpha * acc[i][j][q];
      }
    }
  }
}

// =====================================================================
// r12 on-the-fly GEMM (fallback path when ws too small)
// =====================================================================
template<int TRANSB>
__global__ __launch_bounds__(256)
void gemm_bf16x3(const float* __restrict__ A, const float* __restrict__ B,
                 const float* __restrict__ bias, float* __restrict__ C,
                 int M, int N, int K, float alpha,
                 long long strideA, long long strideB, long long strideC)
{
  constexpr int LK = 40;
  __shared__ unsigned short Ah[128 * LK], Al[128 * LK];
  __shared__ unsigned short Bh[128 * LK], Bl[128 * LK];

  const int z = blockIdx.z;
  A += (size_t)z * strideA;
  B += (size_t)z * strideB;
  C += (size_t)z * strideC;

  const int tid  = threadIdx.x;
  const int row0 = blockIdx.x * 128;
  const int col0 = blockIdx.y * 128;
  const int w    = tid >> 6;
  const int lane = tid & 63;
  const int m0   = (w >> 1) * 64;
  const int n0   = (w & 1) * 64;
  const int half = lane >> 4;
  const int mr   = lane & 15;

  f32x4 acc[4][4];
#pragma unroll
  for (int i = 0; i < 4; ++i)
#pragma unroll
    for (int j = 0; j < 4; ++j) acc[i][j] = (f32x4){0.f, 0.f, 0.f, 0.f};

  for (int k0 = 0; k0 < K; k0 += 32) {
    __syncthreads();
    {
      const int r = tid >> 3, c4 = tid & 7;
#pragma unroll
      for (int rep = 0; rep < 4; ++rep) {
        const int row = r + rep * 32;
        const float4 v = *(const float4*)&A[(size_t)(row0 + row) * K + k0 + c4 * 4];
        unsigned short h0,h1,h2,h3,l0,l1,l2,l3;
        split_bf16(v.x, h0, l0); split_bf16(v.y, h1, l1);
        split_bf16(v.z, h2, l2); split_bf16(v.w, h3, l3);
        *(u16x4*)&Ah[row * LK + c4 * 4] = (u16x4){h0, h1, h2, h3};
        *(u16x4*)&Al[row * LK + c4 * 4] = (u16x4){l0, l1, l2, l3};
      }
    }
    if (TRANSB) {
      const int r = tid >> 3, c4 = tid & 7;
#pragma unroll
      for (int rep = 0; rep < 4; ++rep) {
        const int row = r + rep * 32;
        const float4 v = *(const float4*)&B[(size_t)(col0 + row) * K + k0 + c4 * 4];
        unsigned short h0,h1,h2,h3,l0,l1,l2,l3;
        split_bf16(v.x, h0, l0); split_bf16(v.y, h1, l1);
        split_bf16(v.z, h2, l2); split_bf16(v.w, h3, l3);
        *(u16x4*)&Bh[row * LK + c4 * 4] = (u16x4){h0, h1, h2, h3};
        *(u16x4*)&Bl[row * LK + c4 * 4] = (u16x4){l0, l1, l2, l3};
      }
    } else {
      const int kk8 = tid >> 5, n4 = tid & 31;
#pragma unroll
      for (int rep = 0; rep < 4; ++rep) {
        const int kk = kk8 + rep * 8;
        const float4 v = *(const float4*)&B[(size_t)(k0 + kk) * N + col0 + n4 * 4];
        unsigned short h, l;
        split_bf16(v.x, h, l); Bh[(n4*4+0)*LK + kk] = h; Bl[(n4*4+0)*LK + kk] = l;
        split_bf16(v.y, h, l); Bh[(n4*4+1)*LK + kk] = h; Bl[(n4*4+1)*LK + kk] = l;
        split_bf16(v.z, h, l); Bh[(n4*4+2)*LK + kk] = h; Bl[(n4*4+2)*LK + kk] = l;
        split_bf16(v.w, h, l); Bh[(n4*4+3)*LK + kk] = h; Bl[(n4*4+3)*LK + kk] = l;
      }
    }
    __syncthreads();

    s16x8 ah[4], al[4], bh[4], bl[4];
#pragma unroll
    for (int i = 0; i < 4; ++i) {
      ah[i] = *(const s16x8*)&Ah[(m0 + i*16 + mr) * LK + half * 8];
      al[i] = *(const s16x8*)&Al[(m0 + i*16 + mr) * LK + half * 8];
      bh[i] = *(const s16x8*)&Bh[(n0 + i*16 + mr) * LK + half * 8];
      bl[i] = *(const s16x8*)&Bl[(n0 + i*16 + mr) * LK + half * 8];
    }
#pragma unroll
    for (int i = 0; i < 4; ++i)
#pragma unroll
      for (int j = 0; j < 4; ++j) {
        acc[i][j] = __builtin_amdgcn_mfma_f32_16x16x32_bf16(ah[i], bh[j], acc[i][j], 0, 0, 0);
        acc[i][j] = __builtin_amdgcn_mfma_f32_16x16x32_bf16(ah[i], bl[j], acc[i][j], 0, 0, 0);
        acc[i][j] = __builtin_amdgcn_mfma_f32_16x16x32_bf16(al[i], bh[j], acc[i][j], 0, 0, 0);
      }
  }

#pragma unroll
  for (int j = 0; j < 4; ++j) {
    const int col = col0 + n0 + j * 16 + mr;
    const float bb = bias ? bias[col] : 0.f;
#pragma unroll
    for (int i = 0; i < 4; ++i) {
#pragma unroll
      for (int q = 0; q < 4; ++q) {
        const int row = row0 + m0 + i * 16 + half * 4 + q;
        C[(size_t)row * N + col] = fmaf(alpha, acc[i][j][q], bb);
      }
    }
  }
}

// =====================================================================
// tanh without an OCML call (abs err ~1e-7)
// =====================================================================
__device__ __forceinline__ float fast_tanh(float x) {
  const float a = fabsf(x);
  const float e = __expf(2.0f * a);
  const float t = 1.0f - 2.0f / (e + 1.0f);
  return copysignf(t, x);
}

// =====================================================================
// RNN scan v9 (r11/r12/r15 EXACT — best validated: 3.83 ms/scan over
// 12 tried variants; r16's probe/store edits reverted as regressions).
// Dual-visibility data-as-flag; wave0 poll + LDS broadcast; weight
// frags + pre hoisted ahead of the barrier; wave0 coalesced dual-store.
// Scan BIT-IDENTICAL (canary: absmax exactly 0.0009765625).
// =====================================================================
__global__ __launch_bounds__(512, 1)
void rnn_scan(const float* __restrict__ Pre, float* __restrict__ Hout,
              const float* __restrict__ Whh, const float* __restrict__ bhh)
{
  __shared__ float wS[32][DIM];                 // 128 KB
  __shared__ __align__(16) float hbuf[2][DIM];  // 8 KB
  __shared__ float pS[8][8];
  const int b    = blockIdx.x & 7;
  const int p    = blockIdx.x >> 3;      // 0..31
  const int wv   = threadIdx.x >> 6;     // 0..7
  const int lane = threadIdx.x & 63;
  const int fl   = ((lane & 1) << 1) | ((lane >> 1) & 1);  // bitrev2

  const float* PreB = Pre  + (size_t)b * SEQ * DIM;
  float*       HB   = Hout + (size_t)b * SEQ * DIM;

  for (int i = threadIdx.x; i < 32 * (DIM / 4); i += 512) {
    const int row = i >> 8, c4 = i & 255;
    *(f32x4*)&wS[row][c4 * 4] =
        *(const f32x4*)&Whh[(size_t)(p * 32 + row) * DIM + c4 * 4];
  }
  __syncthreads();

  const bool w0lane = (wv == 0) && (lane < 32);
  const float biasv = w0lane ? bhh[p * 32 + lane] : 0.f;

  for (int t = 0; t < SEQ; ++t) {
    float pre = 0.f;
    if (w0lane) pre = PreB[(size_t)t * DIM + p * 32 + lane];

    f32x4 wr[4][4];
    if (wv != 0) {
#pragma unroll
      for (int r = 0; r < 4; ++r) {
        wr[r][0] = *(const f32x4*)&wS[wv * 4 + r][  0 + lane * 4];
        wr[r][1] = *(const f32x4*)&wS[wv * 4 + r][256 + lane * 4];
        wr[r][2] = *(const f32x4*)&wS[wv * 4 + r][512 + lane * 4];
        wr[r][3] = *(const f32x4*)&wS[wv * 4 + r][768 + lane * 4];
      }
    }

    if (t > 0) {
      if (wv == 0) {
        const float* hp = HB + (size_t)(t - 1) * DIM;
        const float* q0 = hp +   0 + lane * 4;
        const float* q1 = hp + 256 + lane * 4;
        const float* q2 = hp + 512 + lane * 4;
        const float* q3 = hp + 768 + lane * 4;
        f32x4 m0, m1, m2, m3;
        while (true) {
          f32x4 f0, f1, f2, f3;
          asm volatile(                      // FAST: own-XCD L2 view
            "global_load_dwordx4 %0, %4, off sc0\n\t"
            "global_load_dwordx4 %1, %5, off sc0\n\t"
            "global_load_dwordx4 %2, %6, off sc0\n\t"
            "global_load_dwordx4 %3, %7, off sc0\n\t"
            "s_waitcnt vmcnt(0)"
            : "=&v"(f0), "=&v"(f1), "=&v"(f2), "=&v"(f3)
            : "v"(q0), "v"(q1), "v"(q2), "v"(q3));
          bool gf = true;
#pragma unroll
          for (int j = 0; j < 4; ++j) {
            gf = gf && (__float_as_uint(f0[j]) != 0xFFFFFFFFu)
                    && (__float_as_uint(f1[j]) != 0xFFFFFFFFu)
                    && (__float_as_uint(f2[j]) != 0xFFFFFFFFu)
                    && (__float_as_uint(f3[j]) != 0xFFFFFFFFu);
          }
          if (__all(gf)) { m0 = f0; m1 = f1; m2 = f2; m3 = f3; break; }

          f32x4 s0, s1, s2, s3;
          asm volatile(                      // SLOW: L3 view (always correct)
            "global_load_dwordx4 %0, %4, off sc0 sc1\n\t"
            "global_load_dwordx4 %1, %5, off sc0 sc1\n\t"
            "global_load_dwordx4 %2, %6, off sc0 sc1\n\t"
            "global_load_dwordx4 %3, %7, off sc0 sc1\n\t"
            "s_waitcnt vmcnt(0)"
            : "=&v"(s0), "=&v"(s1), "=&v"(s2), "=&v"(s3)
            : "v"(q0), "v"(q1), "v"(q2), "v"(q3));
          bool gm = true;
#pragma unroll
          for (int j = 0; j < 4; ++j) {
            m0[j] = (__float_as_uint(f0[j]) != 0xFFFFFFFFu) ? f0[j] : s0[j];
            m1[j] = (__float_as_uint(f1[j]) != 0xFFFFFFFFu) ? f1[j] : s1[j];
            m2[j] = (__float_as_uint(f2[j]) != 0xFFFFFFFFu) ? f2[j] : s2[j];
            m3[j] = (__float_as_uint(f3[j]) != 0xFFFFFFFFu) ? f3[j] : s3[j];
            gm = gm && (__float_as_uint(m0[j]) != 0xFFFFFFFFu)
                    && (__float_as_uint(m1[j]) != 0xFFFFFFFFu)
                    && (__float_as_uint(m2[j]) != 0xFFFFFFFFu)
                    && (__float_as_uint(m3[j]) != 0xFFFFFFFFu);
          }
          if (__all(gm)) break;
        }
        *(f32x4*)&hbuf[t & 1][  0 + lane * 4] = m0;
        *(f32x4*)&hbuf[t & 1][256 + lane * 4] = m1;
        *(f32x4*)&hbuf[t & 1][512 + lane * 4] = m2;
        *(f32x4*)&hbuf[t & 1][768 + lane * 4] = m3;
#pragma unroll
        for (int r = 0; r < 4; ++r) {
          wr[r][0] = *(const f32x4*)&wS[wv * 4 + r][  0 + lane * 4];
          wr[r][1] = *(const f32x4*)&wS[wv * 4 + r][256 + lane * 4];
          wr[r][2] = *(const f32x4*)&wS[wv * 4 + r][512 + lane * 4];
          wr[r][3] = *(const f32x4*)&wS[wv * 4 + r][768 + lane * 4];
        }
      }
      __syncthreads();   // A: hbuf ready
      const f32x4 h0 = *(const f32x4*)&hbuf[t & 1][  0 + lane * 4];
      const f32x4 h1 = *(const f32x4*)&hbuf[t & 1][256 + lane * 4];
      const f32x4 h2 = *(const f32x4*)&hbuf[t & 1][512 + lane * 4];
      const f32x4 h3 = *(const f32x4*)&hbuf[t & 1][768 + lane * 4];
      float acc[4];
#pragma unroll
      for (int r = 0; r < 4; ++r) {
        float a = 0.f;
        a = fmaf(wr[r][0].x, h0.x, fmaf(wr[r][0].y, h0.y,
            fmaf(wr[r][0].z, h0.z, fmaf(wr[r][0].w, h0.w, a))));
        a = fmaf(wr[r][1].x, h1.x, fmaf(wr[r][1].y, h1.y,
            fmaf(wr[r][1].z, h1.z, fmaf(wr[r][1].w, h1.w, a))));
        a = fmaf(wr[r][2].x, h2.x, fmaf(wr[r][2].y, h2.y,
            fmaf(wr[r][2].z, h2.z, fmaf(wr[r][2].w, h2.w, a))));
        a = fmaf(wr[r][3].x, h3.x, fmaf(wr[r][3].y, h3.y,
            fmaf(wr[r][3].z, h3.z, fmaf(wr[r][3].w, h3.w, a))));
        acc[r] = a;
      }
#pragma unroll
      for (int m = 0; m < 2; ++m) {
        const int mask = 1 << m;
        const int nv   = 2 >> m;
        const bool up  = (lane & mask) != 0;
#pragma unroll
        for (int r = 0; r < nv; ++r) {
          const float lo = up ? acc[r + nv] : acc[r];
          const float hi = up ? acc[r] : acc[r + nv];
          acc[r] = lo + __shfl_xor(hi, mask);
        }
      }
#pragma unroll
      for (int off = 4; off < 64; off <<= 1) acc[0] += __shfl_xor(acc[0], off);

      if (lane < 4) pS[wv][fl] = acc[0];
      __syncthreads();   // B: pS ready
    }

    if (w0lane) {
      float s = (t > 0) ? (pre + pS[lane >> 2][lane & 3] + biasv)
                        : (pre + biasv);
      const float v = fast_tanh(s);
      float* dst = HB + (size_t)t * DIM + p * 32 + lane;
      asm volatile(
        "global_store_dword %0, %1, off sc0\n\t"
        "global_store_dword %0, %1, off sc0 sc1"
        :: "v"(dst), "v"(v));
    }
  }
}

// =====================================================================
// Masked softmax, in place, one row per block
// =====================================================================
__global__ __launch_bounds__(256)
void softmax_mask(float* __restrict__ S, const unsigned char* __restrict__ mask)
{
  const size_t row = (size_t)blockIdx.y * gridDim.x + blockIdx.x;
  float* p = S + row * SEQ;
  const unsigned char* mrow = mask + row * SEQ;
  __shared__ float buf[SEQ];
  __shared__ float red[4];
  const int tid = threadIdx.x, lane = tid & 63, wv = tid >> 6;

  float mx = -1e30f;
  for (int i = tid; i < SEQ; i += 256) {
    const float v = mrow[i] ? -1e9f : p[i];
    buf[i] = v;
    mx = fmaxf(mx, v);
  }
#pragma unroll
  for (int off = 1; off < 64; off <<= 1) mx = fmaxf(mx, __shfl_xor(mx, off));
  if (lane == 0) red[wv] = mx;
  __syncthreads();
  mx = fmaxf(fmaxf(red[0], red[1]), fmaxf(red[2], red[3]));

  float s = 0.f;
  for (int i = tid; i < SEQ; i += 256) {
    const float e = __expf(buf[i] - mx);
    buf[i] = e;
    s += e;
  }
#pragma unroll
  for (int off = 1; off < 64; off <<= 1) s += __shfl_xor(s, off);
  __syncthreads();
  if (lane == 0) red[wv] = s;
  __syncthreads();
  s = red[0] + red[1] + red[2] + red[3];
  const float inv = 1.f / s;
  for (int i = tid; i < SEQ; i += 256) p[i] = buf[i] * inv;
}

// =====================================================================
extern "C" void kernel_launch(void* const* d_in, const int* in_sizes, int n_in,
                              void* d_out, int out_size, void* d_ws, size_t ws_size,
                              hipStream_t stream)
{
  (void)in_sizes; (void)n_in; (void)out_size;
  const unsigned char* mask = (const unsigned char*)d_in[0];
  const float* reps = (const float*)d_in[1];
  const float* Wih  = (const float*)d_in[2];
  const float* Whh  = (const float*)d_in[3];
  const float* bih  = (const float*)d_in[4];
  const float* bhh  = (const float*)d_in[5];
  const float* Wq   = (const float*)d_in[6];
  const float* bq   = (const float*)d_in[7];
  const float* Wk   = (const float*)d_in[8];
  const float* bk   = (const float*)d_in[9];
  const float* Wv   = (const float*)d_in[10];
  const float* bv   = (const float*)d_in[11];
  const float* Wo   = (const float*)d_in[12];
  const float* bo   = (const float*)d_in[13];
  float* out = (float*)d_out;

  char* ws = (char*)d_ws;
  float* Hb = (float*)(ws);
  float* Qb = (float*)(ws + ((size_t)64  << 20));
  float* Kb = (float*)(ws + ((size_t)128 << 20));
  float* Vb = (float*)(ws + ((size_t)192 << 20));
  float* Sb = (float*)(ws + ((size_t)256 << 20));
  const size_t needFull = ((size_t)256 << 20) + (size_t)BATCH * SEQ * SEQ * 4;
  const bool fullS = ws_size >= needFull;
  const size_t MM = (size_t)DIM * DIM;
  unsigned short* wsp = (unsigned short*)(ws + needFull);
  const bool presplit = fullS && (ws_size >= needFull + ((size_t)20 << 20));
  const size_t hBytes = (size_t)BATCH * SEQ * DIM * 4;

  const int M1 = BATCH * SEQ;
  const size_t PL = (size_t)M1 * DIM;
  const float scale = 0.03125f;
  const dim3 blk(256);
  const dim3 projGrid(M1/128, DIM/128, 1);
  const long long sSD = (long long)SEQ * DIM;
  const long long sSS = (long long)SEQ * SEQ;
  const int splitGrid = (int)(MM / (256 * 4));

  unsigned short* Qh = (unsigned short*)Qb;  unsigned short* Ql = Qh + PL;
  unsigned short* Kh = (unsigned short*)Kb;  unsigned short* Kl = Kh + PL;
  unsigned short* Vth = (unsigned short*)Vb; unsigned short* Vtl = Vth + PL;

  const float* X = reps;
  for (int l = 0; l < NLAYER; ++l) {
    const size_t wof = (size_t)l * DIM * DIM;
    const size_t bof = (size_t)l * DIM;
    float* Y = (l == NLAYER - 1) ? out : Qb;

    hipMemsetAsync(Hb, 0xFF, hBytes, stream);
    if (presplit) {
      split_mat<<<splitGrid, blk, 0, stream>>>(Wih + wof, wsp + 0*MM, wsp + 1*MM);
      split_mat<<<splitGrid, blk, 0, stream>>>(Wq  + wof, wsp + 2*MM, wsp + 3*MM);
      split_mat<<<splitGrid, blk, 0, stream>>>(Wk  + wof, wsp + 4*MM, wsp + 5*MM);
      split_mat<<<splitGrid, blk, 0, stream>>>(Wv  + wof, wsp + 6*MM, wsp + 7*MM);
      split_mat<<<splitGrid, blk, 0, stream>>>(Wo  + wof, wsp + 8*MM, wsp + 9*MM);

      gemm_bsplit<0><<<projGrid, blk, 0, stream>>>(
          X, wsp + 0*MM, wsp + 1*MM, bih + bof, Kb, nullptr, nullptr,
          M1, DIM, DIM, 1.f, 0, 0, 0);
      rnn_scan<<<dim3(256), dim3(512), 0, stream>>>(Kb, Hb, Whh + wof, bhh + bof);

      gemm_bsplit<1><<<projGrid, blk, 0, stream>>>(
          Hb, wsp + 2*MM, wsp + 3*MM, bq + bof, nullptr, Qh, Ql,
          M1, DIM, DIM, 1.f, 0, 0, 0);
      gemm_bsplit<1><<<projGrid, blk, 0, stream>>>(
          Hb, wsp + 4*MM, wsp + 5*MM, bk + bof, nullptr, Kh, Kl,
          M1, DIM, DIM, 1.f, 0, 0, 0);
      gemm_bsplit<0><<<projGrid, blk, 0, stream>>>(
          Hb, wsp + 6*MM, wsp + 7*MM, bv + bof, Sb, nullptr, nullptr,
          M1, DIM, DIM, 1.f, 0, 0, 0);
      vtrans<<<dim3(SEQ/64, DIM/64, BATCH), blk, 0, stream>>>(Sb, Vth, Vtl);

      gemm_absplit<<<dim3(SEQ/128, SEQ/128, BATCH), blk, 0, stream>>>(
          Qh, Ql, Kh, Kl, Sb, SEQ, SEQ, DIM, scale, sSD, sSD, sSS);
      softmax_mask<<<dim3(SEQ, BATCH), blk, 0, stream>>>(Sb, mask);
      gemm_bsplit<0><<<dim3(SEQ/128, DIM/128, BATCH), blk, 0, stream>>>(
          Sb, Vth, Vtl, nullptr, Hb, nullptr, nullptr,
          SEQ, DIM, SEQ, 1.f, sSS, (long long)DIM * SEQ, sSD);
      gemm_bsplit<0><<<projGrid, blk, 0, stream>>>(
          Hb, wsp + 8*MM, wsp + 9*MM, bo + bof, Y, nullptr, nullptr,
          M1, DIM, DIM, 1.f, 0, 0, 0);
    } else {
      gemm_bf16x3<1><<<projGrid, blk, 0, stream>>>(
          X, Wih + wof, bih + bof, Kb, M1, DIM, DIM, 1.f, 0, 0, 0);
      rnn_scan<<<dim3(256), dim3(512), 0, stream>>>(Kb, Hb, Whh + wof, bhh + bof);
      gemm_bf16x3<1><<<projGrid, blk, 0, stream>>>(
          Hb, Wq + wof, bq + bof, Qb, M1, DIM, DIM, 1.f, 0, 0, 0);
      gemm_bf16x3<1><<<projGrid, blk, 0, stream>>>(
          Hb, Wk + wof, bk + bof, Kb, M1, DIM, DIM, 1.f, 0, 0, 0);
      gemm_bf16x3<1><<<projGrid, blk, 0, stream>>>(
          Hb, Wv + wof, bv + bof, Vb, M1, DIM, DIM, 1.f, 0, 0, 0);
      if (fullS) {
        gemm_bf16x3<1><<<dim3(SEQ/128, SEQ/128, BATCH), blk, 0, stream>>>(
            Qb, Kb, nullptr, Sb, SEQ, SEQ, DIM, scale, sSD, sSD, sSS);
        softmax_mask<<<dim3(SEQ, BATCH), blk, 0, stream>>>(Sb, mask);
        gemm_bf16x3<0><<<dim3(SEQ/128, DIM/128, BATCH), blk, 0, stream>>>(
            Sb, Vb, nullptr, Hb, SEQ, DIM, SEQ, 1.f, sSS, sSD, sSD);
      } else {
        for (int bb = 0; bb < BATCH; ++bb) {
          gemm_bf16x3<1><<<dim3(SEQ/128, SEQ/128, 1), blk, 0, stream>>>(
              Qb + (size_t)bb * sSD, Kb + (size_t)bb * sSD, nullptr, Sb,
              SEQ, SEQ, DIM, scale, 0, 0, 0);
          softmax_mask<<<dim3(SEQ, 1), blk, 0, stream>>>(Sb, mask + (size_t)bb * sSS);
          gemm_bf16x3<0><<<dim3(SEQ/128, DIM/128, 1), blk, 0, stream>>>(
              Sb, Vb + (size_t)bb * sSD, nullptr, Hb + (size_t)bb * sSD,
              SEQ, DIM, SEQ, 1.f, 0, 0, 0);
        }
      }
      gemm_bf16x3<1><<<projGrid, blk, 0, stream>>>(
          Hb, Wo + wof, bo + bof, Y, M1, DIM, DIM, 1.f, 0, 0, 0);
    }
    X = Y;
  }
}